// Round 3
// baseline (501.603 us; speedup 1.0000x reference)
//
#include <hip/hip_runtime.h>
#include <hip/hip_bf16.h>

#define N_NODES 50000
#define N_EDGES 800000
#define NC 16
#define FDIM 13
#define HID 32
#define RT_ROW 528     // 16 outputs * 32 hidden + 16 b2-terms (bf16)
#define EPB 64         // edges per msg tile

// big-ws path: padded-bucket sort (no scan, no separate scatter)
#define BSH 3          // bucket = 8 nodes, lambda = 128 edges
#define NBUCK 6250
#define CAP 192        // lambda + ~5.7 sigma; spill list covers the tail
#define TPB 3          // tiles per bucket = CAP/EPB
#define NTILES (NBUCK * TPB)   // 18750
#define OVB 2
#define OVCAP 4096

// fallback path (R9-proven): exact counting sort
#define NBUCK9 6400    // ceil(50000/8) padded to 256*25
#define MTILE 12500

typedef unsigned short ushort_t;
typedef unsigned int uint_t;
typedef __attribute__((ext_vector_type(8))) unsigned short u16x8;

__device__ __forceinline__ float bf2f(ushort_t u) {
  union { unsigned int i; float f; } v; v.i = ((unsigned int)u) << 16; return v.f;
}
__device__ __forceinline__ ushort_t f2bf(float f) {
  union { unsigned int i; float f; } v; v.f = f;
  unsigned int r = v.i + 0x7FFFu + ((v.i >> 16) & 1u);   // RNE
  return (ushort_t)(r >> 16);
}
__device__ __forceinline__ float loadf(const void* p, int i, int isf32) {
  return isf32 ? ((const float*)p)[i] : bf2f(((const ushort_t*)p)[i]);
}
__device__ __forceinline__ float sigmoidf_(float x) { return 1.0f / (1.0f + __expf(-x)); }
__device__ __forceinline__ float tanhf_(float x) { return 1.0f - 2.0f / (__expf(2.0f * x) + 1.0f); }

// packed bf16 pair dot-accumulate: d = a.lo*b.lo + a.hi*b.hi + c  (R9-proven)
__device__ __forceinline__ float dot2bf(uint_t a, uint_t b, float c) {
  float d;
  asm("v_dot2_f32_bf16 %0, %1, %2, %3" : "=v"(d) : "v"(a), "v"(b), "v"(c));
  return d;
}

// ballot-based dtype detect (1 = fp32 inputs); no LDS atomics (R8 lesson)
__device__ __forceinline__ int detect_f32(const void* hx_in) {
  __shared__ int wc[4];
  int tid = threadIdx.x;
  uint_t lo = ((const uint_t*)hx_in)[tid] & 0xFFFFu;
  uint_t ex = (lo >> 7) & 0xFFu;
  int wild = (ex < 103u || ex > 151u) && lo != 0u && lo != 0x8000u;
  unsigned long long m = __ballot(wild);
  if ((tid & 63) == 0) wc[tid >> 6] = __popcll(m);
  __syncthreads();
  int c = wc[0] + wc[1] + wc[2] + wc[3];
  __syncthreads();
  return c > 64;
}

__device__ __forceinline__ void stage_w2(const void* w2, const void* b2,
                                         float* w2t, float* b2s, int isf32) {
  int tid = threadIdx.x;
  for (int k = tid; k < 256 * HID; k += 256) {
    int h = k >> 8, io = k & 255;
    w2t[io * 36 + h] = loadf(w2, h * 256 + io, isf32);
  }
  b2s[tid] = loadf(b2, tid, isf32);
}

// Rt row build (fallback path): lane owns output o; hxr[16] = node row
__device__ __forceinline__ void rt_row(const float* hxr, const float* w2t,
                                       const float* b2s, ushort_t* rowp, int o) {
  #pragma unroll
  for (int c = 0; c < 4; c++) {
    float a8[8] = {0, 0, 0, 0, 0, 0, 0, 0};
    #pragma unroll
    for (int i = 0; i < 16; i++) {
      const float* wp = &w2t[(i * 16 + o) * 36 + c * 8];
      float4 wa = *(const float4*)(wp);
      float4 wb = *(const float4*)(wp + 4);
      a8[0] += hxr[i] * wa.x; a8[1] += hxr[i] * wa.y; a8[2] += hxr[i] * wa.z; a8[3] += hxr[i] * wa.w;
      a8[4] += hxr[i] * wb.x; a8[5] += hxr[i] * wb.y; a8[6] += hxr[i] * wb.z; a8[7] += hxr[i] * wb.w;
    }
    u16x8 ov;
    #pragma unroll
    for (int j = 0; j < 8; j++) ov[j] = f2bf(a8[j]);
    *(u16x8*)(rowp + o * 32 + c * 8) = ov;
  }
  float vb = 0.0f;
  #pragma unroll
  for (int i = 0; i < 16; i++) vb += hxr[i] * b2s[i * 16 + o];
  rowp[512 + o] = f2bf(vb);
}

// ============ shared Rt-GEMM pieces (bf16 W2 in LDS, f32 math) ============
// W2h layout: [i][col] col<512: col=o*32+h -> w2[h][i*16+o]; col 512+o -> b2[i*16+o]
// stride 536 shorts (1072 B, 16B-aligned rows).
__device__ __forceinline__ void stage_w2h(const void* w2, const void* b2,
                                          ushort_t* W2h, int isf32, int tid) {
  for (int k = tid; k < 256 * HID; k += 256) {
    int h = k >> 8, io = k & 255;
    int i = io >> 4, o = io & 15;
    ushort_t val = isf32 ? f2bf(((const float*)w2)[k]) : ((const ushort_t*)w2)[k];
    W2h[i * 536 + o * 32 + h] = val;
  }
  { int i = tid >> 4, o = tid & 15;
    ushort_t val = isf32 ? f2bf(((const float*)b2)[tid]) : ((const ushort_t*)b2)[tid];
    W2h[i * 536 + 512 + o] = val; }
}

// register-tiled GEMM: 64-node tile [64x16] @ [16x528] -> bf16 Rt rows.
// thread = 4 nodes x 8 cols; 1 ds_read_b128 per (i,chunk), broadcast across 16 node-groups.
__device__ __forceinline__ void rt_gemm(const ushort_t* W2h, const float* hxs,
                                        ushort_t* Rt, int n0, int tid) {
  int ng = tid & 15, chl = tid >> 4;           // 16 node-groups x 16 chunk-lanes
  float hxr[4][16];
  #pragma unroll
  for (int a = 0; a < 4; a++) {
    const float* hp = &hxs[(ng * 4 + a) * 20];
    #pragma unroll
    for (int q = 0; q < 4; q++) {
      float4 t = *(const float4*)(hp + 4 * q);
      hxr[a][4 * q + 0] = t.x; hxr[a][4 * q + 1] = t.y;
      hxr[a][4 * q + 2] = t.z; hxr[a][4 * q + 3] = t.w;
    }
  }
  for (int ch = chl; ch < 66; ch += 16) {      // 66 chunks of 8 cols = 528
    float acc[4][8];
    #pragma unroll
    for (int a = 0; a < 4; a++)
      #pragma unroll
      for (int j = 0; j < 8; j++) acc[a][j] = 0.0f;
    #pragma unroll
    for (int i = 0; i < 16; i++) {
      u16x8 wv = *(const u16x8*)&W2h[i * 536 + ch * 8];
      float w[8];
      #pragma unroll
      for (int j = 0; j < 8; j++) w[j] = bf2f(wv[j]);
      #pragma unroll
      for (int a = 0; a < 4; a++) {
        float hv = hxr[a][i];
        #pragma unroll
        for (int j = 0; j < 8; j++) acc[a][j] += hv * w[j];
      }
    }
    #pragma unroll
    for (int a = 0; a < 4; a++) {
      int n = n0 + ng * 4 + a;
      if (n < N_NODES) {
        u16x8 ov;
        #pragma unroll
        for (int j = 0; j < 8; j++) ov[j] = f2bf(acc[a][j]);
        *(u16x8*)(Rt + (size_t)n * RT_ROW + ch * 8) = ov;
      }
    }
  }
}

// ============ BIG PATH ============
// kernel 1: block-specialized fusion. bid%5==0 -> Rt GEMM block (reads hx_in
// directly; independent of edge work, fills edge blocks' idle issue slots).
// Others -> per-edge work (detect + hx->fp32 + agg zero + deg/cnt atomics +
// bucket scatter + MLP hidden). Union LDS 22.3KB -> 7 blocks/CU.
__global__ void __launch_bounds__(256) k_pre(
    const void* __restrict__ hx_in, const void* __restrict__ ef,
    const int* __restrict__ src, const int* __restrict__ dst,
    const void* __restrict__ w1, const void* __restrict__ b1,
    const void* __restrict__ w2, const void* __restrict__ b2,
    float* __restrict__ hx32, float* __restrict__ agg, float* __restrict__ deg,
    int* __restrict__ cnt, int* __restrict__ ovfcnt, int* __restrict__ ovf,
    uint2* __restrict__ sortbuf, ushort_t* __restrict__ hidden,
    ushort_t* __restrict__ Rt) {
  __shared__ __align__(16) char smem[22272];
  int tid = threadIdx.x;
  int isf32 = detect_f32(hx_in);
  int bid = blockIdx.x;
  int g = bid / 5, r = bid - g * 5;

  if (r == 0) {
    // ===== rt block g (782 total): Rt from ORIGINAL hx_in =====
    ushort_t* W2h = (ushort_t*)smem;           // 17152 B
    float* hxs = (float*)(smem + 17152);       // 64*20*4 = 5120 B
    stage_w2h(w2, b2, W2h, isf32, tid);
    int n0 = g * 64;
    for (int k = tid; k < 64 * 16; k += 256) {
      int nl = k >> 4, c = k & 15;
      int n = n0 + nl;
      hxs[nl * 20 + c] = (n < N_NODES) ? loadf(hx_in, n * 16 + c, isf32) : 0.0f;
    }
    __syncthreads();
    rt_gemm(W2h, hxs, Rt, n0, tid);
    return;
  }

  int eb = g * 4 + (r - 1);
  if (eb >= 3125) return;
  // ===== edge block =====
  float* w1s = (float*)smem;                   // 416*4 = 1664 B
  float* b1s = (float*)(smem + 1664);          // 128 B
  float* efs = (float*)(smem + 1792);          // 256*13*4 = 13312 B
  int e0 = eb * 256;
  int e = e0 + tid;
  int s = src[e], d = dst[e];
  atomicAdd(&deg[d], 1.0f);                    // issue atomics early
  int b = s >> BSH;
  int p = atomicAdd(&cnt[b], 1);               // 6250 counters: R5-proven contention
  if (p < CAP) {
    uint2 rec; rec.x = ((uint_t)s << 16) | (uint_t)d; rec.y = (uint_t)e;
    sortbuf[b * CAP + p] = rec;
  } else {
    int op = atomicAdd(ovfcnt, 1);
    if (op < OVCAP) ovf[op] = e;
  }
  for (int k = tid; k < FDIM * HID; k += 256) w1s[k] = loadf(w1, k, isf32);
  if (tid < HID) b1s[tid] = loadf(b1, tid, isf32);
  for (int k = tid; k < 256 * FDIM; k += 256)  // coalesced ef tile stage
    efs[k] = loadf(ef, e0 * FDIM + k, isf32);
  float hv = loadf(hx_in, e, isf32);
  hx32[e] = hv;
  agg[e] = 0.0f;
  __syncthreads();
  float efr[FDIM];
  #pragma unroll
  for (int i = 0; i < FDIM; i++) efr[i] = efs[tid * FDIM + i];  // stride-13: conflict-free
  u16x8* hrow = (u16x8*)(hidden + (size_t)e * HID);
  #pragma unroll
  for (int c = 0; c < 4; c++) {
    float a8[8];
    #pragma unroll
    for (int j = 0; j < 8; j++) a8[j] = b1s[c * 8 + j];
    #pragma unroll
    for (int i = 0; i < FDIM; i++) {
      float4 wa = *(const float4*)&w1s[i * HID + c * 8];
      float4 wb = *(const float4*)&w1s[i * HID + c * 8 + 4];
      a8[0] += efr[i] * wa.x; a8[1] += efr[i] * wa.y;
      a8[2] += efr[i] * wa.z; a8[3] += efr[i] * wa.w;
      a8[4] += efr[i] * wb.x; a8[5] += efr[i] * wb.y;
      a8[6] += efr[i] * wb.z; a8[7] += efr[i] * wb.w;
    }
    u16x8 ov;
    #pragma unroll
    for (int j = 0; j < 8; j++) ov[j] = f2bf(fmaxf(a8[j], 0.0f));
    hrow[c] = ov;
  }
}

// kernel 2/4: per-edge message — gather 64 B hidden rows, dot2 with Rt, scatter
__global__ void __launch_bounds__(256) k_msg_big(
    const int* __restrict__ src, const int* __restrict__ dst,
    const int* __restrict__ cnt, const int* __restrict__ ovfcnt,
    const int* __restrict__ ovf, const uint2* __restrict__ sortbuf,
    const ushort_t* __restrict__ hidden, const ushort_t* __restrict__ Rt,
    float* __restrict__ agg) {
  __shared__ uint_t hsp[EPB * 20];             // 16 bf16-pairs/edge, stride 20
  __shared__ int ssrc[EPB], sdst[EPB], seid[EPB];
  int tid = threadIdx.x;
  int t = blockIdx.x;
  if (t < NTILES) {
    int b = t / TPB, ls0 = (t - b * TPB) * EPB;
    int cb = cnt[b]; if (cb > CAP) cb = CAP;
    int nv = cb - ls0; if (nv <= 0) return;    // uniform early exit
    if (nv > EPB) nv = EPB;
    if (tid < EPB) {
      uint2 rec;
      if (tid < nv) rec = sortbuf[b * CAP + ls0 + tid];
      else { rec.x = 0u; rec.y = 0u; }
      ssrc[tid] = (int)(rec.x >> 16); sdst[tid] = (int)(rec.x & 0xFFFFu);
      seid[tid] = (int)rec.y;
    }
    __syncthreads();
    {
      int row = tid >> 2, chunk = tid & 3;     // 4 lanes per 64 B row
      uint4 hv = ((const uint4*)(hidden + (size_t)seid[row] * HID))[chunk];
      int base = row * 20 + chunk * 4;
      hsp[base] = hv.x; hsp[base + 1] = hv.y; hsp[base + 2] = hv.z; hsp[base + 3] = hv.w;
    }
    __syncthreads();
    #pragma unroll
    for (int q = 0; q < 4; q++) {
      int item = q * 256 + tid, le = item >> 4, o = item & 15;
      if (le < nv) {
        int s = ssrc[le], d = sdst[le];
        const ushort_t* rrow = Rt + (size_t)s * RT_ROW;
        const uint_t* ru = (const uint_t*)(rrow + o * 32);
        const uint_t* hp = &hsp[le * 20];
        float acc = bf2f(rrow[512 + o]);
        #pragma unroll
        for (int k = 0; k < 16; k++) acc = dot2bf(hp[k], ru[k], acc);
        atomicAdd(&agg[d * NC + o], acc);
      }
    }
  } else {
    // spill edges (normally zero)
    int on = *ovfcnt; if (on > OVCAP) on = OVCAP;
    for (int i = (t - NTILES) * 256 + tid; i < on * NC; i += OVB * 256) {
      int e = ovf[i >> 4], o = i & 15;
      int s = src[e], d = dst[e];
      const ushort_t* rrow = Rt + (size_t)s * RT_ROW;
      const uint_t* ru = (const uint_t*)(rrow + o * 32);
      const uint_t* hp = (const uint_t*)(hidden + (size_t)e * HID);
      float acc = bf2f(rrow[512 + o]);
      for (int k = 0; k < 16; k++) acc = dot2bf(hp[k], ru[k], acc);
      atomicAdd(&agg[d * NC + o], acc);
    }
  }
}

// ============ GRU pieces (shared by both paths) ============
__device__ __forceinline__ void stage_gru(const void* w_ih, const void* w_hh,
                                          const void* b_ih, const void* b_hh,
                                          float* wihT, float* whhT,
                                          float* bih, float* bhh, int isf32, int tid) {
  for (int kk = tid; kk < 3 * NC * NC; kk += 256) {
    int g = kk >> 8, rem = kk & 255, o = rem >> 4, k = rem & 15;
    wihT[g * 272 + k * 17 + o] = loadf(w_ih, kk, isf32);
    whhT[g * 272 + k * 17 + o] = loadf(w_hh, kk, isf32);
  }
  if (tid < 3 * NC) { bih[tid] = loadf(b_ih, tid, isf32); bhh[tid] = loadf(b_hh, tid, isf32); }
}
__device__ __forceinline__ float gru_core(const float* wihT, const float* whhT,
                                          const float* bih, const float* bhh,
                                          const float* x, const float* h, int o) {
  float gir = bih[o], giz = bih[NC + o], gin = bih[2 * NC + o];
  float ghr = bhh[o], ghz = bhh[NC + o], ghn = bhh[2 * NC + o];
  #pragma unroll
  for (int k = 0; k < NC; k++) {
    gir += x[k] * wihT[k * 17 + o];
    giz += x[k] * wihT[272 + k * 17 + o];
    gin += x[k] * wihT[544 + k * 17 + o];
    ghr += h[k] * whhT[k * 17 + o];
    ghz += h[k] * whhT[272 + k * 17 + o];
    ghn += h[k] * whhT[544 + k * 17 + o];
  }
  float r = sigmoidf_(gir + ghr);
  float z = sigmoidf_(giz + ghz);
  float n = tanhf_(gin + r * ghn);
  return (1.0f - z) * n + z * h[o];
}
__device__ __forceinline__ void load_xh(const float* agg, const float* hx, int v,
                                        float inv, float* x, float* h) {
  const float4* ar = (const float4*)(agg + v * NC);
  const float4* hr = (const float4*)(hx + v * NC);
  #pragma unroll
  for (int q = 0; q < 4; q++) {
    float4 aa = ar[q], bb = hr[q];
    x[4 * q + 0] = aa.x * inv; x[4 * q + 1] = aa.y * inv; x[4 * q + 2] = aa.z * inv; x[4 * q + 3] = aa.w * inv;
    h[4 * q + 0] = bb.x; h[4 * q + 1] = bb.y; h[4 * q + 2] = bb.z; h[4 * q + 3] = bb.w;
  }
}

// kernel 3: fused GRU update + Rt rebuild + agg re-zero. Block = 64 nodes;
// GRU writes hn to LDS, barrier, Rt GEMM consumes it (no hx32 round-trip).
__global__ void __launch_bounds__(256) k_upd_rt(
    const void* __restrict__ hx_in, const float* __restrict__ agg_in,
    const float* __restrict__ deg, float* __restrict__ hx,
    const void* __restrict__ w_ih, const void* __restrict__ w_hh,
    const void* __restrict__ b_ih, const void* __restrict__ b_hh,
    const void* __restrict__ w2, const void* __restrict__ b2,
    ushort_t* __restrict__ Rt, float* __restrict__ agg_out) {
  __shared__ __align__(16) char smem[29184];
  ushort_t* W2h = (ushort_t*)smem;             // 17152 B
  float* hxs  = (float*)(smem + 17152);        // 5120 B
  float* wihT = (float*)(smem + 22272);        // 3264 B
  float* whhT = (float*)(smem + 25536);        // 3264 B
  float* bihs = (float*)(smem + 28800);        // 192 B
  float* bhhs = (float*)(smem + 28992);        // 192 B
  int tid = threadIdx.x;
  int isf32 = detect_f32(hx_in);
  stage_gru(w_ih, w_hh, b_ih, b_hh, wihT, whhT, bihs, bhhs, isf32, tid);
  stage_w2h(w2, b2, W2h, isf32, tid);
  __syncthreads();

  int n0 = blockIdx.x * 64;
  int o = tid & 15;
  float hn[4];
  #pragma unroll
  for (int q = 0; q < 4; q++) {
    int vl = (tid >> 4) + q * 16;
    int v = n0 + vl;
    if (v < N_NODES) {
      float inv = 1.0f / fmaxf(deg[v], 1.0f);
      float x[16], h[16];
      load_xh(agg_in, hx, v, inv, x, h);
      hn[q] = gru_core(wihT, whhT, bihs, bhhs, x, h, o);
    } else hn[q] = 0.0f;
  }
  __syncthreads();                 // all agg/hx row reads done (rows block-local)
  #pragma unroll
  for (int q = 0; q < 4; q++) {
    int vl = (tid >> 4) + q * 16;
    int v = n0 + vl;
    hxs[vl * 20 + o] = hn[q];
    if (v < N_NODES) {
      hx[v * NC + o] = hn[q];
      agg_out[v * NC + o] = 0.0f;
    }
  }
  __syncthreads();
  rt_gemm(W2h, hxs, Rt, n0, tid);
}

// kernel 5: final GRU -> d_out
__global__ void __launch_bounds__(256) k_gru(
    const void* __restrict__ hx_in, const float* __restrict__ agg,
    const float* __restrict__ deg, const float* __restrict__ hx,
    const void* __restrict__ w_ih, const void* __restrict__ w_hh,
    const void* __restrict__ b_ih, const void* __restrict__ b_hh,
    void* __restrict__ out) {
  __shared__ float wihT[816], whhT[816], bih[48], bhh[48];
  int tid = threadIdx.x;
  int isf32 = detect_f32(hx_in);
  stage_gru(w_ih, w_hh, b_ih, b_hh, wihT, whhT, bih, bhh, isf32, tid);
  __syncthreads();
  int idx = blockIdx.x * 256 + tid;
  int v = idx >> 4, o = idx & 15;
  float inv = 1.0f / fmaxf(deg[v], 1.0f);
  float x[16], h[16];
  load_xh(agg, hx, v, inv, x, h);
  float hn = gru_core(wihT, whhT, bih, bhh, x, h, o);
  if (isf32) ((float*)out)[idx] = hn;
  else       ((ushort_t*)out)[idx] = f2bf(hn);
}

// ============ FALLBACK PATH (R9-proven, detect inline) ============
__global__ void k_pre9(const void* __restrict__ hx_in, float* __restrict__ hx32,
                       const int* __restrict__ src, const int* __restrict__ dst,
                       float* __restrict__ deg, int* __restrict__ hist) {
  int isf32 = detect_f32(hx_in);
  int idx = blockIdx.x * 256 + threadIdx.x;
  hx32[idx] = loadf(hx_in, idx, isf32);
  atomicAdd(&deg[dst[idx]], 1.0f);
  atomicAdd(&hist[src[idx] >> BSH], 1);
}

__global__ void k_scan_rnode9(const void* __restrict__ hx_in, int* __restrict__ hist,
                              const float* __restrict__ hx, const void* __restrict__ w2,
                              const void* __restrict__ b2, ushort_t* __restrict__ Rt,
                              float* __restrict__ agg) {
  __shared__ int lds[NBUCK9];
  __shared__ int psum[256];
  __shared__ float w2t[256 * 36];
  __shared__ float b2s[256];
  int tid = threadIdx.x;
  if (blockIdx.x == 0) {
    for (int i = tid; i < NBUCK9; i += 256) lds[i] = hist[i];
    __syncthreads();
    int base = tid * 25, s = 0;
    #pragma unroll
    for (int i = 0; i < 25; i++) { int v = lds[base + i]; lds[base + i] = s; s += v; }
    psum[tid] = s;
    __syncthreads();
    if (tid == 0) { int run = 0; for (int i = 0; i < 256; i++) { int v = psum[i]; psum[i] = run; run += v; } }
    __syncthreads();
    int off = psum[tid];
    #pragma unroll
    for (int i = 0; i < 25; i++) lds[base + i] += off;
    __syncthreads();
    for (int i = tid; i < NBUCK9; i += 256) hist[i] = lds[i];
    return;
  }
  int isf32 = detect_f32(hx_in);
  stage_w2(w2, b2, w2t, b2s, isf32);
  __syncthreads();
  int idx = (blockIdx.x - 1) * 256 + tid;
  agg[idx] = 0.0f;
  int node = idx >> 4, o = idx & 15;
  float hxr[16];
  const float4* hp = (const float4*)(hx + node * NC);
  #pragma unroll
  for (int q = 0; q < 4; q++) {
    float4 t = hp[q];
    hxr[4 * q + 0] = t.x; hxr[4 * q + 1] = t.y; hxr[4 * q + 2] = t.z; hxr[4 * q + 3] = t.w;
  }
  rt_row(hxr, w2t, b2s, Rt + (size_t)node * RT_ROW, o);
}

__global__ void k_scatter9(const int* __restrict__ src, const int* __restrict__ dst,
                           int* __restrict__ cursors, uint2* __restrict__ sortbuf) {
  int e = blockIdx.x * 256 + threadIdx.x;
  int s = src[e];
  int p = atomicAdd(&cursors[s >> BSH], 1);
  uint2 rec; rec.x = ((uint_t)s << 16) | (uint_t)dst[e]; rec.y = (uint_t)e;
  sortbuf[p] = rec;
}

__global__ void __launch_bounds__(256) k_msg9(
    const void* __restrict__ hx_in, const uint2* __restrict__ sortbuf,
    const void* __restrict__ ef, const void* __restrict__ w1,
    const void* __restrict__ b1, const ushort_t* __restrict__ Rt,
    float* __restrict__ agg) {
  __shared__ float w1s[FDIM * HID];
  __shared__ float b1s[HID];
  __shared__ float efs[EPB * FDIM];
  __shared__ uint_t hsp[EPB * 20];
  __shared__ int ssrc[EPB], sdst[EPB], seid[EPB];
  int tid = threadIdx.x;
  int isf32 = detect_f32(hx_in);
  int e0 = blockIdx.x * EPB;
  for (int k = tid; k < FDIM * HID; k += 256) w1s[k] = loadf(w1, k, isf32);
  if (tid < HID) b1s[tid] = loadf(b1, tid, isf32);
  if (tid < EPB) {
    uint2 rec = sortbuf[e0 + tid];
    ssrc[tid] = (int)(rec.x >> 16); sdst[tid] = (int)(rec.x & 0xFFFFu);
    seid[tid] = (int)rec.y;
  }
  __syncthreads();
  #pragma unroll
  for (int q = 0; q < 4; q++) {
    int j = q * 256 + tid, le = j >> 4, i = j & 15;
    if (i < FDIM) efs[le * FDIM + i] = loadf(ef, seid[le] * FDIM + i, isf32);
  }
  __syncthreads();
  #pragma unroll
  for (int q = 0; q < 4; q++) {
    int v = q * 256 + tid;
    int le = v >> 4, hp2 = v & 15, h0 = hp2 * 2;
    float a0 = b1s[h0], a1 = b1s[h0 + 1];
    #pragma unroll
    for (int i = 0; i < FDIM; i++) {
      float e = efs[le * FDIM + i];
      a0 += e * w1s[i * HID + h0];
      a1 += e * w1s[i * HID + h0 + 1];
    }
    hsp[le * 20 + hp2] = (uint_t)f2bf(fmaxf(a0, 0.0f)) | ((uint_t)f2bf(fmaxf(a1, 0.0f)) << 16);
  }
  __syncthreads();
  #pragma unroll
  for (int q = 0; q < 4; q++) {
    int item = q * 256 + tid, le = item >> 4, o = item & 15;
    int s = ssrc[le], d = sdst[le];
    const ushort_t* rrow = Rt + (size_t)s * RT_ROW;
    const uint_t* ru = (const uint_t*)(rrow + o * 32);
    const uint_t* hp = &hsp[le * 20];
    float acc = bf2f(rrow[512 + o]);
    #pragma unroll
    for (int k = 0; k < 16; k++) acc = dot2bf(hp[k], ru[k], acc);
    atomicAdd(&agg[d * NC + o], acc);
  }
}

extern "C" void kernel_launch(void* const* d_in, const int* in_sizes, int n_in,
                              void* d_out, int out_size, void* d_ws, size_t ws_size,
                              hipStream_t stream) {
  const void* hx_in = d_in[0];
  const void* ef    = d_in[1];
  const int*  esrc  = (const int*)d_in[2];
  const int*  edst  = (const int*)d_in[3];
  const void* w1    = d_in[4];
  const void* b1    = d_in[5];
  const void* w2    = d_in[6];
  const void* b2    = d_in[7];
  const void* wih   = d_in[8];
  const void* whh   = d_in[9];
  const void* bih_g = d_in[10];
  const void* bhh_g = d_in[11];

  char* ws = (char*)d_ws;
  float* hx32   = (float*)(ws + 0);          //  3,200,000
  float* agg    = (float*)(ws + 3200000);    //  3,200,000
  float* deg    = (float*)(ws + 6400000);    //    200,000  -- zero region start
  int*   cnt    = (int*)  (ws + 6600000);    //     25,600  (cnt / hist)
  int*   ovfcnt = (int*)  (ws + 6625600);    //         32  -- zero region end
  int*   ovf    = (int*)  (ws + 6625632);    //     16,384
  // big path layout:
  uint2*    sortbufB = (uint2*)(ws + 6642016);       //  9,600,000 (6250*192*8)
  ushort_t* hiddenB  = (ushort_t*)(ws + 16242016);   // 51,200,000
  ushort_t* RtB      = (ushort_t*)(ws + 67442016);   // 52,800,000 -> 120,242,016
  // fallback layout:
  uint2*    sortbuf9 = (uint2*)(ws + 6642016);       //  6,400,000
  ushort_t* Rt9      = (ushort_t*)(ws + 13042016);   // 52,800,000 -> 65,842,016

  int big = (ws_size >= (size_t)120242016);
  hipMemsetAsync(ws + 6400000, 0, 225632, stream);   // deg + cnt + ovfcnt

  if (big) {
    k_pre<<<3910, 256, 0, stream>>>(hx_in, ef, esrc, edst, w1, b1, w2, b2,
                                    hx32, agg, deg, cnt, ovfcnt, ovf,
                                    sortbufB, hiddenB, RtB);
    k_msg_big<<<NTILES + OVB, 256, 0, stream>>>(esrc, edst, cnt, ovfcnt, ovf,
                                                sortbufB, hiddenB, RtB, agg);
    k_upd_rt<<<782, 256, 0, stream>>>(hx_in, agg, deg, hx32, wih, whh, bih_g, bhh_g,
                                      w2, b2, RtB, agg);
    k_msg_big<<<NTILES + OVB, 256, 0, stream>>>(esrc, edst, cnt, ovfcnt, ovf,
                                                sortbufB, hiddenB, RtB, agg);
    k_gru<<<3125, 256, 0, stream>>>(hx_in, agg, deg, hx32, wih, whh, bih_g, bhh_g, d_out);
  } else {
    k_pre9<<<3125, 256, 0, stream>>>(hx_in, hx32, esrc, edst, deg, cnt);
    k_scan_rnode9<<<3126, 256, 0, stream>>>(hx_in, cnt, hx32, w2, b2, Rt9, agg);
    k_scatter9<<<3125, 256, 0, stream>>>(esrc, edst, cnt, sortbuf9);
    k_msg9<<<MTILE, 256, 0, stream>>>(hx_in, sortbuf9, ef, w1, b1, Rt9, agg);
    k_upd_rt<<<782, 256, 0, stream>>>(hx_in, agg, deg, hx32, wih, whh, bih_g, bhh_g,
                                      w2, b2, Rt9, agg);
    k_msg9<<<MTILE, 256, 0, stream>>>(hx_in, sortbuf9, ef, w1, b1, Rt9, agg);
    k_gru<<<3125, 256, 0, stream>>>(hx_in, agg, deg, hx32, wih, whh, bih_g, bhh_g, d_out);
  }
}

// Round 4
// 453.276 us; speedup vs baseline: 1.1066x; 1.1066x over previous
//
#include <hip/hip_runtime.h>
#include <hip/hip_bf16.h>

#define N_NODES 50000
#define N_EDGES 800000
#define NC 16
#define FDIM 13
#define HID 32
#define RT_ROW 528     // 16 outputs * 32 hidden + 16 b2-terms (bf16)
#define EPB 64         // edges per msg tile

// big-ws path: padded-bucket sort (no scan, no separate scatter)
#define BSH 3          // bucket = 8 nodes, lambda = 128 edges
#define NBUCK 6250
#define CAP 192        // lambda + ~5.7 sigma; spill list covers the tail
#define TPB 3          // tiles per bucket = CAP/EPB
#define NTILES (NBUCK * TPB)   // 18750
#define OVB 2
#define OVCAP 4096

// fallback path (R9-proven): exact counting sort
#define NBUCK9 6400    // ceil(50000/8) padded to 256*25
#define MTILE 12500

typedef unsigned short ushort_t;
typedef unsigned int uint_t;
typedef __attribute__((ext_vector_type(8))) unsigned short u16x8;

__device__ __forceinline__ float bf2f(ushort_t u) {
  union { unsigned int i; float f; } v; v.i = ((unsigned int)u) << 16; return v.f;
}
__device__ __forceinline__ ushort_t f2bf(float f) {
  union { unsigned int i; float f; } v; v.f = f;
  unsigned int r = v.i + 0x7FFFu + ((v.i >> 16) & 1u);   // RNE
  return (ushort_t)(r >> 16);
}
__device__ __forceinline__ float loadf(const void* p, int i, int isf32) {
  return isf32 ? ((const float*)p)[i] : bf2f(((const ushort_t*)p)[i]);
}
__device__ __forceinline__ float sigmoidf_(float x) { return 1.0f / (1.0f + __expf(-x)); }
__device__ __forceinline__ float tanhf_(float x) { return 1.0f - 2.0f / (__expf(2.0f * x) + 1.0f); }

// packed bf16 pair dot-accumulate: d = a.lo*b.lo + a.hi*b.hi + c  (R9-proven)
__device__ __forceinline__ float dot2bf(uint_t a, uint_t b, float c) {
  float d;
  asm("v_dot2_f32_bf16 %0, %1, %2, %3" : "=v"(d) : "v"(a), "v"(b), "v"(c));
  return d;
}

// ballot-based dtype detect (1 = fp32 inputs); no LDS atomics (R8 lesson)
__device__ __forceinline__ int detect_f32(const void* hx_in) {
  __shared__ int wc[4];
  int tid = threadIdx.x;
  uint_t lo = ((const uint_t*)hx_in)[tid] & 0xFFFFu;
  uint_t ex = (lo >> 7) & 0xFFu;
  int wild = (ex < 103u || ex > 151u) && lo != 0u && lo != 0x8000u;
  unsigned long long m = __ballot(wild);
  if ((tid & 63) == 0) wc[tid >> 6] = __popcll(m);
  __syncthreads();
  int c = wc[0] + wc[1] + wc[2] + wc[3];
  __syncthreads();
  return c > 64;
}

__device__ __forceinline__ void stage_w2(const void* w2, const void* b2,
                                         float* w2t, float* b2s, int isf32) {
  int tid = threadIdx.x;
  for (int k = tid; k < 256 * HID; k += 256) {
    int h = k >> 8, io = k & 255;
    w2t[io * 36 + h] = loadf(w2, h * 256 + io, isf32);
  }
  b2s[tid] = loadf(b2, tid, isf32);
}

// Rt row build (fallback path): lane owns output o; hxr[16] = node row
__device__ __forceinline__ void rt_row(const float* hxr, const float* w2t,
                                       const float* b2s, ushort_t* rowp, int o) {
  #pragma unroll
  for (int c = 0; c < 4; c++) {
    float a8[8] = {0, 0, 0, 0, 0, 0, 0, 0};
    #pragma unroll
    for (int i = 0; i < 16; i++) {
      const float* wp = &w2t[(i * 16 + o) * 36 + c * 8];
      float4 wa = *(const float4*)(wp);
      float4 wb = *(const float4*)(wp + 4);
      a8[0] += hxr[i] * wa.x; a8[1] += hxr[i] * wa.y; a8[2] += hxr[i] * wa.z; a8[3] += hxr[i] * wa.w;
      a8[4] += hxr[i] * wb.x; a8[5] += hxr[i] * wb.y; a8[6] += hxr[i] * wb.z; a8[7] += hxr[i] * wb.w;
    }
    u16x8 ov;
    #pragma unroll
    for (int j = 0; j < 8; j++) ov[j] = f2bf(a8[j]);
    *(u16x8*)(rowp + o * 32 + c * 8) = ov;
  }
  float vb = 0.0f;
  #pragma unroll
  for (int i = 0; i < 16; i++) vb += hxr[i] * b2s[i * 16 + o];
  rowp[512 + o] = f2bf(vb);
}

// ============ bf16 W2 staging (R3-validated numerics) ============
// W2h layout: [i][col] col<512: col=o*32+h -> w2[h][i*16+o]; col 512+o -> b2[i*16+o]
// stride 536 shorts (1072 B, 16B-aligned rows).
__device__ __forceinline__ void stage_w2h(const void* w2, const void* b2,
                                          ushort_t* W2h, int isf32, int tid) {
  for (int k = tid; k < 256 * HID; k += 256) {
    int h = k >> 8, io = k & 255;
    int i = io >> 4, o = io & 15;
    ushort_t val = isf32 ? f2bf(((const float*)w2)[k]) : ((const ushort_t*)w2)[k];
    W2h[i * 536 + o * 32 + h] = val;
  }
  { int i = tid >> 4, o = tid & 15;
    ushort_t val = isf32 ? f2bf(((const float*)b2)[tid]) : ((const ushort_t*)b2)[tid];
    W2h[i * 536 + 512 + o] = val; }
}

// ============ BIG PATH ============
// kernel 1: per-edge work only (R1-proven: 118us, occ 73%, VGPR 28).
__global__ void __launch_bounds__(256) k_edge(
    const void* __restrict__ hx_in, const void* __restrict__ ef,
    const int* __restrict__ src, const int* __restrict__ dst,
    const void* __restrict__ w1, const void* __restrict__ b1,
    float* __restrict__ hx32, float* __restrict__ agg, float* __restrict__ deg,
    int* __restrict__ cnt, int* __restrict__ ovfcnt, int* __restrict__ ovf,
    uint2* __restrict__ sortbuf, ushort_t* __restrict__ hidden) {
  __shared__ __align__(16) float w1s[FDIM * HID];
  __shared__ float b1s[HID];
  __shared__ float efs[256 * FDIM];
  int tid = threadIdx.x;
  int isf32 = detect_f32(hx_in);
  int e0 = blockIdx.x * 256;
  int e = e0 + tid;                            // grid 3125 covers E == N*NC
  int s = src[e], d = dst[e];
  atomicAdd(&deg[d], 1.0f);                    // issue atomics early; staging hides latency
  int b = s >> BSH;
  int p = atomicAdd(&cnt[b], 1);               // 6250 counters: R5-proven contention
  if (p < CAP) {
    uint2 rec; rec.x = ((uint_t)s << 16) | (uint_t)d; rec.y = (uint_t)e;
    sortbuf[b * CAP + p] = rec;
  } else {
    int op = atomicAdd(ovfcnt, 1);
    if (op < OVCAP) ovf[op] = e;
  }
  for (int k = tid; k < FDIM * HID; k += 256) w1s[k] = loadf(w1, k, isf32);
  if (tid < HID) b1s[tid] = loadf(b1, tid, isf32);
  for (int k = tid; k < 256 * FDIM; k += 256)  // coalesced ef tile stage
    efs[k] = loadf(ef, e0 * FDIM + k, isf32);
  float hv = loadf(hx_in, e, isf32);
  hx32[e] = hv;
  agg[e] = 0.0f;
  __syncthreads();
  float efr[FDIM];
  #pragma unroll
  for (int i = 0; i < FDIM; i++) efr[i] = efs[tid * FDIM + i];  // stride-13: conflict-free
  u16x8* hrow = (u16x8*)(hidden + (size_t)e * HID);
  #pragma unroll
  for (int c = 0; c < 4; c++) {
    float a8[8];
    #pragma unroll
    for (int j = 0; j < 8; j++) a8[j] = b1s[c * 8 + j];
    #pragma unroll
    for (int i = 0; i < FDIM; i++) {
      float4 wa = *(const float4*)&w1s[i * HID + c * 8];
      float4 wb = *(const float4*)&w1s[i * HID + c * 8 + 4];
      a8[0] += efr[i] * wa.x; a8[1] += efr[i] * wa.y;
      a8[2] += efr[i] * wa.z; a8[3] += efr[i] * wa.w;
      a8[4] += efr[i] * wb.x; a8[5] += efr[i] * wb.y;
      a8[6] += efr[i] * wb.z; a8[7] += efr[i] * wb.w;
    }
    u16x8 ov;
    #pragma unroll
    for (int j = 0; j < 8; j++) ov[j] = f2bf(fmaxf(a8[j], 0.0f));
    hrow[c] = ov;
  }
}

// kernel 1b (redesigned): Rt GEMM, 32-node tiles -> 1563 blocks (6.1/CU vs 3/CU
// before), bf16 weights (19.8KB LDS total -> 8 blocks/CU cap), thread = 2 nodes
// x 8 cols. Weight reads: 4 distinct 16B lines/wave (chl 0..3), 16-way ng
// broadcast -> conflict-free. Write-floor ~11us; target <=18us (was ~40).
__global__ void __launch_bounds__(256) k_rt2(
    const void* __restrict__ hx_in, const float* __restrict__ hx,
    const void* __restrict__ w2, const void* __restrict__ b2,
    ushort_t* __restrict__ Rt) {
  __shared__ __align__(16) ushort_t W2h[16 * 536];   // 17152 B
  __shared__ __align__(16) float hxs[32 * 20];       //  2560 B
  int tid = threadIdx.x;
  int isf32 = detect_f32(hx_in);
  stage_w2h(w2, b2, W2h, isf32, tid);
  int n0 = blockIdx.x * 32;
  for (int k = tid; k < 32 * 16; k += 256) {
    int nl = k >> 4, c = k & 15;
    int n = n0 + nl;
    hxs[nl * 20 + c] = (n < N_NODES) ? hx[n * 16 + c] : 0.0f;
  }
  __syncthreads();
  int ng = tid & 15, chl = tid >> 4;           // 16 node-groups x 16 chunk-lanes
  float hxr[2][16];
  #pragma unroll
  for (int a = 0; a < 2; a++) {
    const float* hp = &hxs[(ng * 2 + a) * 20];
    #pragma unroll
    for (int q = 0; q < 4; q++) {
      float4 t = *(const float4*)(hp + 4 * q);
      hxr[a][4 * q + 0] = t.x; hxr[a][4 * q + 1] = t.y;
      hxr[a][4 * q + 2] = t.z; hxr[a][4 * q + 3] = t.w;
    }
  }
  for (int ch = chl; ch < 66; ch += 16) {      // 66 chunks of 8 cols = 528
    float acc[2][8];
    #pragma unroll
    for (int a = 0; a < 2; a++)
      #pragma unroll
      for (int j = 0; j < 8; j++) acc[a][j] = 0.0f;
    #pragma unroll
    for (int i = 0; i < 16; i++) {
      u16x8 wv = *(const u16x8*)&W2h[i * 536 + ch * 8];
      float w[8];
      #pragma unroll
      for (int j = 0; j < 8; j++) w[j] = bf2f(wv[j]);
      #pragma unroll
      for (int a = 0; a < 2; a++) {
        float hv = hxr[a][i];
        #pragma unroll
        for (int j = 0; j < 8; j++) acc[a][j] += hv * w[j];
      }
    }
    #pragma unroll
    for (int a = 0; a < 2; a++) {
      int n = n0 + ng * 2 + a;
      if (n < N_NODES) {
        u16x8 ov;
        #pragma unroll
        for (int j = 0; j < 8; j++) ov[j] = f2bf(acc[a][j]);
        *(u16x8*)(Rt + (size_t)n * RT_ROW + ch * 8) = ov;
      }
    }
  }
}

// kernel 2/4: per-edge message — gather 64 B hidden rows, dot2 with Rt, scatter
__global__ void __launch_bounds__(256) k_msg_big(
    const int* __restrict__ src, const int* __restrict__ dst,
    const int* __restrict__ cnt, const int* __restrict__ ovfcnt,
    const int* __restrict__ ovf, const uint2* __restrict__ sortbuf,
    const ushort_t* __restrict__ hidden, const ushort_t* __restrict__ Rt,
    float* __restrict__ agg) {
  __shared__ uint_t hsp[EPB * 20];             // 16 bf16-pairs/edge, stride 20
  __shared__ int ssrc[EPB], sdst[EPB], seid[EPB];
  int tid = threadIdx.x;
  int t = blockIdx.x;
  if (t < NTILES) {
    int b = t / TPB, ls0 = (t - b * TPB) * EPB;
    int cb = cnt[b]; if (cb > CAP) cb = CAP;
    int nv = cb - ls0; if (nv <= 0) return;    // uniform early exit
    if (nv > EPB) nv = EPB;
    if (tid < EPB) {
      uint2 rec;
      if (tid < nv) rec = sortbuf[b * CAP + ls0 + tid];
      else { rec.x = 0u; rec.y = 0u; }
      ssrc[tid] = (int)(rec.x >> 16); sdst[tid] = (int)(rec.x & 0xFFFFu);
      seid[tid] = (int)rec.y;
    }
    __syncthreads();
    {
      int row = tid >> 2, chunk = tid & 3;     // 4 lanes per 64 B row
      uint4 hv = ((const uint4*)(hidden + (size_t)seid[row] * HID))[chunk];
      int base = row * 20 + chunk * 4;
      hsp[base] = hv.x; hsp[base + 1] = hv.y; hsp[base + 2] = hv.z; hsp[base + 3] = hv.w;
    }
    __syncthreads();
    #pragma unroll
    for (int q = 0; q < 4; q++) {
      int item = q * 256 + tid, le = item >> 4, o = item & 15;
      if (le < nv) {
        int s = ssrc[le], d = sdst[le];
        const ushort_t* rrow = Rt + (size_t)s * RT_ROW;
        const uint_t* ru = (const uint_t*)(rrow + o * 32);
        const uint_t* hp = &hsp[le * 20];
        float acc = bf2f(rrow[512 + o]);
        #pragma unroll
        for (int k = 0; k < 16; k++) acc = dot2bf(hp[k], ru[k], acc);
        atomicAdd(&agg[d * NC + o], acc);
      }
    }
  } else {
    // spill edges (normally zero)
    int on = *ovfcnt; if (on > OVCAP) on = OVCAP;
    for (int i = (t - NTILES) * 256 + tid; i < on * NC; i += OVB * 256) {
      int e = ovf[i >> 4], o = i & 15;
      int s = src[e], d = dst[e];
      const ushort_t* rrow = Rt + (size_t)s * RT_ROW;
      const uint_t* ru = (const uint_t*)(rrow + o * 32);
      const uint_t* hp = (const uint_t*)(hidden + (size_t)e * HID);
      float acc = bf2f(rrow[512 + o]);
      for (int k = 0; k < 16; k++) acc = dot2bf(hp[k], ru[k], acc);
      atomicAdd(&agg[d * NC + o], acc);
    }
  }
}

// ============ GRU pieces (shared by both paths) ============
__device__ __forceinline__ void stage_gru(const void* w_ih, const void* w_hh,
                                          const void* b_ih, const void* b_hh,
                                          float* wihT, float* whhT,
                                          float* bih, float* bhh, int isf32, int tid) {
  for (int kk = tid; kk < 3 * NC * NC; kk += 256) {
    int g = kk >> 8, rem = kk & 255, o = rem >> 4, k = rem & 15;
    wihT[g * 272 + k * 17 + o] = loadf(w_ih, kk, isf32);
    whhT[g * 272 + k * 17 + o] = loadf(w_hh, kk, isf32);
  }
  if (tid < 3 * NC) { bih[tid] = loadf(b_ih, tid, isf32); bhh[tid] = loadf(b_hh, tid, isf32); }
}
__device__ __forceinline__ float gru_core(const float* wihT, const float* whhT,
                                          const float* bih, const float* bhh,
                                          const float* x, const float* h, int o) {
  float gir = bih[o], giz = bih[NC + o], gin = bih[2 * NC + o];
  float ghr = bhh[o], ghz = bhh[NC + o], ghn = bhh[2 * NC + o];
  #pragma unroll
  for (int k = 0; k < NC; k++) {
    gir += x[k] * wihT[k * 17 + o];
    giz += x[k] * wihT[272 + k * 17 + o];
    gin += x[k] * wihT[544 + k * 17 + o];
    ghr += h[k] * whhT[k * 17 + o];
    ghz += h[k] * whhT[272 + k * 17 + o];
    ghn += h[k] * whhT[544 + k * 17 + o];
  }
  float r = sigmoidf_(gir + ghr);
  float z = sigmoidf_(giz + ghz);
  float n = tanhf_(gin + r * ghn);
  return (1.0f - z) * n + z * h[o];
}
__device__ __forceinline__ void load_xh(const float* agg, const float* hx, int v,
                                        float inv, float* x, float* h) {
  const float4* ar = (const float4*)(agg + v * NC);
  const float4* hr = (const float4*)(hx + v * NC);
  #pragma unroll
  for (int q = 0; q < 4; q++) {
    float4 aa = ar[q], bb = hr[q];
    x[4 * q + 0] = aa.x * inv; x[4 * q + 1] = aa.y * inv; x[4 * q + 2] = aa.z * inv; x[4 * q + 3] = aa.w * inv;
    h[4 * q + 0] = bb.x; h[4 * q + 1] = bb.y; h[4 * q + 2] = bb.z; h[4 * q + 3] = bb.w;
  }
}

// kernel 3: GRU update (in place) + agg re-zero. Lean (7KB LDS, low VGPR).
__global__ void __launch_bounds__(256) k_update(
    const void* __restrict__ hx_in, const float* __restrict__ agg_in,
    const float* __restrict__ deg, float* __restrict__ hx,
    const void* __restrict__ w_ih, const void* __restrict__ w_hh,
    const void* __restrict__ b_ih, const void* __restrict__ b_hh,
    float* __restrict__ agg_out) {
  __shared__ float wihT[816], whhT[816], bih[48], bhh[48];
  int tid = threadIdx.x;
  int isf32 = detect_f32(hx_in);
  stage_gru(w_ih, w_hh, b_ih, b_hh, wihT, whhT, bih, bhh, isf32, tid);
  __syncthreads();
  int idx = blockIdx.x * 256 + tid;
  int v = idx >> 4, o = idx & 15;
  float inv = 1.0f / fmaxf(deg[v], 1.0f);
  float x[16], h[16];
  load_xh(agg_in, hx, v, inv, x, h);
  float hn = gru_core(wihT, whhT, bih, bhh, x, h, o);
  __syncthreads();                 // all row reads done before in-place write (block-local rows)
  hx[idx] = hn;
  agg_out[idx] = 0.0f;
}

// kernel 5: final GRU -> d_out
__global__ void __launch_bounds__(256) k_gru(
    const void* __restrict__ hx_in, const float* __restrict__ agg,
    const float* __restrict__ deg, const float* __restrict__ hx,
    const void* __restrict__ w_ih, const void* __restrict__ w_hh,
    const void* __restrict__ b_ih, const void* __restrict__ b_hh,
    void* __restrict__ out) {
  __shared__ float wihT[816], whhT[816], bih[48], bhh[48];
  int tid = threadIdx.x;
  int isf32 = detect_f32(hx_in);
  stage_gru(w_ih, w_hh, b_ih, b_hh, wihT, whhT, bih, bhh, isf32, tid);
  __syncthreads();
  int idx = blockIdx.x * 256 + tid;
  int v = idx >> 4, o = idx & 15;
  float inv = 1.0f / fmaxf(deg[v], 1.0f);
  float x[16], h[16];
  load_xh(agg, hx, v, inv, x, h);
  float hn = gru_core(wihT, whhT, bih, bhh, x, h, o);
  if (isf32) ((float*)out)[idx] = hn;
  else       ((ushort_t*)out)[idx] = f2bf(hn);
}

// ============ FALLBACK PATH (R9-proven, detect inline) ============
__global__ void k_pre9(const void* __restrict__ hx_in, float* __restrict__ hx32,
                       const int* __restrict__ src, const int* __restrict__ dst,
                       float* __restrict__ deg, int* __restrict__ hist) {
  int isf32 = detect_f32(hx_in);
  int idx = blockIdx.x * 256 + threadIdx.x;
  hx32[idx] = loadf(hx_in, idx, isf32);
  atomicAdd(&deg[dst[idx]], 1.0f);
  atomicAdd(&hist[src[idx] >> BSH], 1);
}

__global__ void k_scan_rnode9(const void* __restrict__ hx_in, int* __restrict__ hist,
                              const float* __restrict__ hx, const void* __restrict__ w2,
                              const void* __restrict__ b2, ushort_t* __restrict__ Rt,
                              float* __restrict__ agg) {
  __shared__ int lds[NBUCK9];
  __shared__ int psum[256];
  __shared__ float w2t[256 * 36];
  __shared__ float b2s[256];
  int tid = threadIdx.x;
  if (blockIdx.x == 0) {
    for (int i = tid; i < NBUCK9; i += 256) lds[i] = hist[i];
    __syncthreads();
    int base = tid * 25, s = 0;
    #pragma unroll
    for (int i = 0; i < 25; i++) { int v = lds[base + i]; lds[base + i] = s; s += v; }
    psum[tid] = s;
    __syncthreads();
    if (tid == 0) { int run = 0; for (int i = 0; i < 256; i++) { int v = psum[i]; psum[i] = run; run += v; } }
    __syncthreads();
    int off = psum[tid];
    #pragma unroll
    for (int i = 0; i < 25; i++) lds[base + i] += off;
    __syncthreads();
    for (int i = tid; i < NBUCK9; i += 256) hist[i] = lds[i];
    return;
  }
  int isf32 = detect_f32(hx_in);
  stage_w2(w2, b2, w2t, b2s, isf32);
  __syncthreads();
  int idx = (blockIdx.x - 1) * 256 + tid;
  agg[idx] = 0.0f;
  int node = idx >> 4, o = idx & 15;
  float hxr[16];
  const float4* hp = (const float4*)(hx + node * NC);
  #pragma unroll
  for (int q = 0; q < 4; q++) {
    float4 t = hp[q];
    hxr[4 * q + 0] = t.x; hxr[4 * q + 1] = t.y; hxr[4 * q + 2] = t.z; hxr[4 * q + 3] = t.w;
  }
  rt_row(hxr, w2t, b2s, Rt + (size_t)node * RT_ROW, o);
}

__global__ void k_scatter9(const int* __restrict__ src, const int* __restrict__ dst,
                           int* __restrict__ cursors, uint2* __restrict__ sortbuf) {
  int e = blockIdx.x * 256 + threadIdx.x;
  int s = src[e];
  int p = atomicAdd(&cursors[s >> BSH], 1);
  uint2 rec; rec.x = ((uint_t)s << 16) | (uint_t)dst[e]; rec.y = (uint_t)e;
  sortbuf[p] = rec;
}

__global__ void __launch_bounds__(256) k_msg9(
    const void* __restrict__ hx_in, const uint2* __restrict__ sortbuf,
    const void* __restrict__ ef, const void* __restrict__ w1,
    const void* __restrict__ b1, const ushort_t* __restrict__ Rt,
    float* __restrict__ agg) {
  __shared__ float w1s[FDIM * HID];
  __shared__ float b1s[HID];
  __shared__ float efs[EPB * FDIM];
  __shared__ uint_t hsp[EPB * 20];
  __shared__ int ssrc[EPB], sdst[EPB], seid[EPB];
  int tid = threadIdx.x;
  int isf32 = detect_f32(hx_in);
  int e0 = blockIdx.x * EPB;
  for (int k = tid; k < FDIM * HID; k += 256) w1s[k] = loadf(w1, k, isf32);
  if (tid < HID) b1s[tid] = loadf(b1, tid, isf32);
  if (tid < EPB) {
    uint2 rec = sortbuf[e0 + tid];
    ssrc[tid] = (int)(rec.x >> 16); sdst[tid] = (int)(rec.x & 0xFFFFu);
    seid[tid] = (int)rec.y;
  }
  __syncthreads();
  #pragma unroll
  for (int q = 0; q < 4; q++) {
    int j = q * 256 + tid, le = j >> 4, i = j & 15;
    if (i < FDIM) efs[le * FDIM + i] = loadf(ef, seid[le] * FDIM + i, isf32);
  }
  __syncthreads();
  #pragma unroll
  for (int q = 0; q < 4; q++) {
    int v = q * 256 + tid;
    int le = v >> 4, hp2 = v & 15, h0 = hp2 * 2;
    float a0 = b1s[h0], a1 = b1s[h0 + 1];
    #pragma unroll
    for (int i = 0; i < FDIM; i++) {
      float e = efs[le * FDIM + i];
      a0 += e * w1s[i * HID + h0];
      a1 += e * w1s[i * HID + h0 + 1];
    }
    hsp[le * 20 + hp2] = (uint_t)f2bf(fmaxf(a0, 0.0f)) | ((uint_t)f2bf(fmaxf(a1, 0.0f)) << 16);
  }
  __syncthreads();
  #pragma unroll
  for (int q = 0; q < 4; q++) {
    int item = q * 256 + tid, le = item >> 4, o = item & 15;
    int s = ssrc[le], d = sdst[le];
    const ushort_t* rrow = Rt + (size_t)s * RT_ROW;
    const uint_t* ru = (const uint_t*)(rrow + o * 32);
    const uint_t* hp = &hsp[le * 20];
    float acc = bf2f(rrow[512 + o]);
    #pragma unroll
    for (int k = 0; k < 16; k++) acc = dot2bf(hp[k], ru[k], acc);
    atomicAdd(&agg[d * NC + o], acc);
  }
}

extern "C" void kernel_launch(void* const* d_in, const int* in_sizes, int n_in,
                              void* d_out, int out_size, void* d_ws, size_t ws_size,
                              hipStream_t stream) {
  const void* hx_in = d_in[0];
  const void* ef    = d_in[1];
  const int*  esrc  = (const int*)d_in[2];
  const int*  edst  = (const int*)d_in[3];
  const void* w1    = d_in[4];
  const void* b1    = d_in[5];
  const void* w2    = d_in[6];
  const void* b2    = d_in[7];
  const void* wih   = d_in[8];
  const void* whh   = d_in[9];
  const void* bih_g = d_in[10];
  const void* bhh_g = d_in[11];

  char* ws = (char*)d_ws;
  float* hx32   = (float*)(ws + 0);          //  3,200,000
  float* agg    = (float*)(ws + 3200000);    //  3,200,000
  float* deg    = (float*)(ws + 6400000);    //    200,000  -- zero region start
  int*   cnt    = (int*)  (ws + 6600000);    //     25,600  (cnt / hist)
  int*   ovfcnt = (int*)  (ws + 6625600);    //         32  -- zero region end
  int*   ovf    = (int*)  (ws + 6625632);    //     16,384
  // big path layout:
  uint2*    sortbufB = (uint2*)(ws + 6642016);       //  9,600,000 (6250*192*8)
  ushort_t* hiddenB  = (ushort_t*)(ws + 16242016);   // 51,200,000
  ushort_t* RtB      = (ushort_t*)(ws + 67442016);   // 52,800,000 -> 120,242,016
  // fallback layout:
  uint2*    sortbuf9 = (uint2*)(ws + 6642016);       //  6,400,000
  ushort_t* Rt9      = (ushort_t*)(ws + 13042016);   // 52,800,000 -> 65,842,016

  int big = (ws_size >= (size_t)120242016);
  hipMemsetAsync(ws + 6400000, 0, 225632, stream);   // deg + cnt + ovfcnt

  if (big) {
    k_edge<<<3125, 256, 0, stream>>>(hx_in, ef, esrc, edst, w1, b1,
                                     hx32, agg, deg, cnt, ovfcnt, ovf,
                                     sortbufB, hiddenB);
    k_rt2<<<1563, 256, 0, stream>>>(hx_in, hx32, w2, b2, RtB);
    k_msg_big<<<NTILES + OVB, 256, 0, stream>>>(esrc, edst, cnt, ovfcnt, ovf,
                                                sortbufB, hiddenB, RtB, agg);
    k_update<<<3125, 256, 0, stream>>>(hx_in, agg, deg, hx32, wih, whh, bih_g, bhh_g,
                                       agg);
    k_rt2<<<1563, 256, 0, stream>>>(hx_in, hx32, w2, b2, RtB);
    k_msg_big<<<NTILES + OVB, 256, 0, stream>>>(esrc, edst, cnt, ovfcnt, ovf,
                                                sortbufB, hiddenB, RtB, agg);
    k_gru<<<3125, 256, 0, stream>>>(hx_in, agg, deg, hx32, wih, whh, bih_g, bhh_g, d_out);
  } else {
    k_pre9<<<3125, 256, 0, stream>>>(hx_in, hx32, esrc, edst, deg, cnt);
    k_scan_rnode9<<<3126, 256, 0, stream>>>(hx_in, cnt, hx32, w2, b2, Rt9, agg);
    k_scatter9<<<3125, 256, 0, stream>>>(esrc, edst, cnt, sortbuf9);
    k_msg9<<<MTILE, 256, 0, stream>>>(hx_in, sortbuf9, ef, w1, b1, Rt9, agg);
    k_update<<<3125, 256, 0, stream>>>(hx_in, agg, deg, hx32, wih, whh, bih_g, bhh_g,
                                       agg);
    k_rt2<<<1563, 256, 0, stream>>>(hx_in, hx32, w2, b2, Rt9);
    k_msg9<<<MTILE, 256, 0, stream>>>(hx_in, sortbuf9, ef, w1, b1, Rt9, agg);
    k_gru<<<3125, 256, 0, stream>>>(hx_in, agg, deg, hx32, wih, whh, bih_g, bhh_g, d_out);
  }
}